// Round 6
// baseline (920.677 us; speedup 1.0000x reference)
//
#include <hip/hip_runtime.h>
#include <math.h>

#define NNODES 100000
#define NEDGES 1600000
#define DIM 64
#define NGRAPHS 64
#define NEG_SLOPE 0.2f
#define SCAN_B 512
#define SCAN_NB ((NNODES + SCAN_B - 1) / SCAN_B)

// ---------------- CSR construction (dst-sorted), self-loops excluded ----------------

__global__ void zero_kernel(int* __restrict__ counts, float* __restrict__ pooled) {
    int i = blockIdx.x * blockDim.x + threadIdx.x;
    if (i <= NNODES) counts[i] = 0;
    if (i < NGRAPHS * DIM) pooled[i] = 0.f;
}

// 4 edges/thread via int4 loads; atomics dominate but load instrs quartered.
__global__ void hist_kernel(const int4* __restrict__ src4, const int4* __restrict__ dst4,
                            int* __restrict__ counts) {
    int e = blockIdx.x * blockDim.x + threadIdx.x;
    if (e < NEDGES / 4) {
        int4 s = src4[e], d = dst4[e];
        if (s.x != d.x) atomicAdd(&counts[d.x], 1);
        if (s.y != d.y) atomicAdd(&counts[d.y], 1);
        if (s.z != d.z) atomicAdd(&counts[d.z], 1);
        if (s.w != d.w) atomicAdd(&counts[d.w], 1);
    }
}

// In-place exclusive scan of counts -> per-block, plus block sums
__global__ void scan1_kernel(int* __restrict__ data, int* __restrict__ bsum) {
    __shared__ int tmp[SCAN_B];
    int t = threadIdx.x;
    int i = blockIdx.x * SCAN_B + t;
    int v = (i < NNODES) ? data[i] : 0;
    tmp[t] = v;
    __syncthreads();
    for (int off = 1; off < SCAN_B; off <<= 1) {
        int a = (t >= off) ? tmp[t - off] : 0;
        __syncthreads();
        if (t >= off) tmp[t] += a;
        __syncthreads();
    }
    if (i < NNODES) data[i] = tmp[t] - v;          // exclusive within block
    if (t == SCAN_B - 1) bsum[blockIdx.x] = tmp[t]; // block total
}

// One-block parallel exclusive scan of the SCAN_NB block sums (SCAN_NB <= 256)
__global__ void scan2_kernel(int* __restrict__ bsum, int* __restrict__ total) {
    __shared__ int tmp[256];
    int t = threadIdx.x;
    int v = (t < SCAN_NB) ? bsum[t] : 0;
    tmp[t] = v;
    __syncthreads();
    for (int off = 1; off < 256; off <<= 1) {
        int a = (t >= off) ? tmp[t - off] : 0;
        __syncthreads();
        if (t >= off) tmp[t] += a;
        __syncthreads();
    }
    if (t < SCAN_NB) bsum[t] = tmp[t] - v;  // exclusive
    if (t == 255) *total = tmp[t];
}

__global__ void scan3_kernel(int* __restrict__ offs, const int* __restrict__ bsum,
                             const int* __restrict__ total, int* __restrict__ cursors) {
    int i = blockIdx.x * SCAN_B + threadIdx.x;
    if (i < NNODES) {
        int o = offs[i] + bsum[blockIdx.x];
        offs[i] = o;
        cursors[i] = o;
    }
    if (i == 0) offs[NNODES] = *total;
}

// Packed (src, val) 8B scatter: halves scattered-store transactions vs two 4B arrays.
// 4 edges/thread via int4/float4 loads.
__global__ void scatter_kernel(const int4* __restrict__ src4, const int4* __restrict__ dst4,
                               const float4* __restrict__ eattr4, int* __restrict__ cursors,
                               int2* __restrict__ csr) {
    int e = blockIdx.x * blockDim.x + threadIdx.x;
    if (e < NEDGES / 4) {
        int4 s = src4[e], d = dst4[e];
        float4 v = eattr4[e];
        if (s.x != d.x) { int p = atomicAdd(&cursors[d.x], 1); csr[p] = make_int2(s.x, __float_as_int(v.x)); }
        if (s.y != d.y) { int p = atomicAdd(&cursors[d.y], 1); csr[p] = make_int2(s.y, __float_as_int(v.y)); }
        if (s.z != d.z) { int p = atomicAdd(&cursors[d.z], 1); csr[p] = make_int2(s.z, __float_as_int(v.z)); }
        if (s.w != d.w) { int p = atomicAdd(&cursors[d.w], 1); csr[p] = make_int2(s.w, __float_as_int(v.w)); }
    }
}

// ---------------- h2 = hin @ W; alpha_d = h2.att[:64]; alpha_s = h2.att[64:128] ----------------
// 256 threads = 4 waves; block handles 16 rows (4 per wave). Wave lane = output column.
// k-outer loop: each W LDS read is shared across 4 row accumulators.
__global__ __launch_bounds__(256) void mm_alpha_kernel(
        const float* __restrict__ hin, const float* __restrict__ W, const float* __restrict__ att,
        float* __restrict__ h2, float* __restrict__ ad, float* __restrict__ as_) {
    __shared__ float wl[DIM * DIM];
    __shared__ float hrow[4 * 4 * DIM];   // 4 waves x 4 rows x 64
    int t = threadIdx.x;
    for (int k = t; k < DIM * DIM; k += 256) wl[k] = W[k];
    __syncthreads();
    int lane = t & 63, w = t >> 6;
    float a0 = att[lane], a1 = att[DIM + lane];
    int rbase = blockIdx.x * 16 + w * 4;
    float* hw = &hrow[w * 4 * DIM];
    #pragma unroll
    for (int r = 0; r < 4; ++r)
        hw[r * DIM + lane] = hin[(size_t)(rbase + r) * DIM + lane];
    // same-wave LDS RAW: ordered, no barrier needed
    float acc0 = 0.f, acc1 = 0.f, acc2 = 0.f, acc3 = 0.f;
    #pragma unroll
    for (int k = 0; k < DIM; ++k) {
        float wlk = wl[k * DIM + lane];
        acc0 = fmaf(hw[0 * DIM + k], wlk, acc0);
        acc1 = fmaf(hw[1 * DIM + k], wlk, acc1);
        acc2 = fmaf(hw[2 * DIM + k], wlk, acc2);
        acc3 = fmaf(hw[3 * DIM + k], wlk, acc3);
    }
    float accs[4] = {acc0, acc1, acc2, acc3};
    #pragma unroll
    for (int r = 0; r < 4; ++r) {
        int i = rbase + r;
        float acc = accs[r];
        h2[(size_t)i * DIM + lane] = acc;
        float vd = acc * a0, vs = acc * a1;
        #pragma unroll
        for (int off = 32; off; off >>= 1) {
            vd += __shfl_xor(vd, off, 64);
            vs += __shfl_xor(vs, off, 64);
        }
        if (lane == 0) { ad[i] = vd; as_[i] = vs; }
    }
}

// ---------------- Per-node GAT aggregation: ONLINE softmax + weighted sum (single pass) ----------
// One wave per node; lane = channel. Self-loop handled inline (edge_attr = 0).
// Deferred-max rescale (THR=8): weights bounded by e^8, normalized at the end.
__global__ __launch_bounds__(256) void gat_agg_kernel(
        const float* __restrict__ h2, const float* __restrict__ ad, const float* __restrict__ as_,
        const int* __restrict__ offs, const int2* __restrict__ csr,
        const float* __restrict__ att, const float* __restrict__ bias, float* __restrict__ hout) {
    int t = threadIdx.x, lane = t & 63, w = t >> 6;
    int i = blockIdx.x * 4 + w;
    float att2 = att[2 * DIM];
    int beg = offs[i], end = offs[i + 1];
    float adi = ad[i];
    // self-loop logit (edge feature 0)
    float ls = adi + as_[i];
    ls = ls >= 0.f ? ls : NEG_SLOPE * ls;
    float m = ls;
    float dsum = (lane == 0) ? 1.f : 0.f;       // exp(ls - ls) = 1, lane-partial
    float acc = h2[(size_t)i * DIM + lane];     // self contribution, weight 1
    for (int e0 = beg; e0 < end; e0 += 64) {
        int e = e0 + lane;
        float l = -INFINITY;
        int s = 0;
        if (e < end) {
            int2 sv = csr[e];                   // coalesced: contiguous per node
            s = sv.x;
            l = adi + as_[s] + __int_as_float(sv.y) * att2;
            l = l >= 0.f ? l : NEG_SLOPE * l;
        }
        float bm = l;
        #pragma unroll
        for (int off = 32; off; off >>= 1) bm = fmaxf(bm, __shfl_xor(bm, off, 64));
        if (bm > m + 8.f) {                     // deferred rescale (wave-uniform branch)
            float sc = __expf(m - bm);
            dsum *= sc; acc *= sc; m = bm;
        }
        float we = __expf(l - m);               // inactive lanes: exp(-inf) = 0
        dsum += we;
        int cnt = min(64, end - e0);
        for (int j = 0; j < cnt; ++j) {
            float wgt = __shfl(we, j, 64);
            int sj = __shfl(s, j, 64);
            acc = fmaf(wgt, h2[(size_t)sj * DIM + lane], acc);
        }
    }
    #pragma unroll
    for (int off = 32; off; off >>= 1) dsum += __shfl_xor(dsum, off, 64);
    float o = acc / dsum + bias[lane];
    hout[(size_t)i * DIM + lane] = fmaxf(o, 0.f);
}

// ---------------- global_add_pool (batch is sorted) + final linear ----------------

__global__ __launch_bounds__(256) void pool_kernel(const float* __restrict__ h,
                                                   const int* __restrict__ batch,
                                                   float* __restrict__ pooled) {
    int t = threadIdx.x, lane = t & 63, w = t >> 6;
    int chunk = blockIdx.x * 4 + w;
    int i0 = chunk * 64;
    if (i0 >= NNODES) return;
    int iend = min(NNODES, i0 + 64);
    int cur = batch[i0];
    float acc = 0.f;
    for (int i = i0; i < iend; ++i) {
        int g = batch[i];                  // sorted: few transitions per chunk
        if (g != cur) { atomicAdd(&pooled[cur * DIM + lane], acc); acc = 0.f; cur = g; }
        acc += h[(size_t)i * DIM + lane];
    }
    atomicAdd(&pooled[cur * DIM + lane], acc);
}

__global__ void final_kernel(const float* __restrict__ pooled, const float* __restrict__ Wf,
                             const float* __restrict__ bf, float* __restrict__ out) {
    int t = threadIdx.x, lane = t & 63, w = t >> 6;
    for (int g = w; g < NGRAPHS; g += 4) {
        float v = pooled[g * DIM + lane] * Wf[lane];
        #pragma unroll
        for (int off = 32; off; off >>= 1) v += __shfl_xor(v, off, 64);
        if (lane == 0) out[g] = v + bf[0];
    }
}

// ---------------- launch ----------------

extern "C" void kernel_launch(void* const* d_in, const int* in_sizes, int n_in,
                              void* d_out, int out_size, void* d_ws, size_t ws_size,
                              hipStream_t stream) {
    const float* x      = (const float*)d_in[0];
    const int*   ei     = (const int*)d_in[1];
    const float* eattr  = (const float*)d_in[2];
    const int*   batch  = (const int*)d_in[3];
    const float* W[3]   = {(const float*)d_in[4], (const float*)d_in[7], (const float*)d_in[10]};
    const float* att[3] = {(const float*)d_in[5], (const float*)d_in[8], (const float*)d_in[11]};
    const float* bia[3] = {(const float*)d_in[6], (const float*)d_in[9], (const float*)d_in[12]};
    const float* Wf = (const float*)d_in[13];
    const float* bf = (const float*)d_in[14];
    float* out = (float*)d_out;
    const int* srcp = ei;            // edge_index row 0
    const int* dstp = ei + NEDGES;   // edge_index row 1

    char* p = (char*)d_ws;
    auto alloc = [&](size_t bytes) { char* r = p; p += (bytes + 255) & ~size_t(255); return r; };
    int*   offs    = (int*)alloc((NNODES + 1) * sizeof(int));
    int*   cursors = (int*)alloc(NNODES * sizeof(int));
    int*   bsum    = (int*)alloc(SCAN_NB * sizeof(int));
    int*   total   = (int*)alloc(sizeof(int));
    int2*  csr     = (int2*)alloc((size_t)NEDGES * sizeof(int2));
    float* h2      = (float*)alloc((size_t)NNODES * DIM * sizeof(float));
    float* ad      = (float*)alloc(NNODES * sizeof(float));
    float* as_     = (float*)alloc(NNODES * sizeof(float));
    float* hbuf    = (float*)alloc((size_t)NNODES * DIM * sizeof(float));
    float* pooled  = (float*)alloc(NGRAPHS * DIM * sizeof(float));

    // CSR build (same work every call; edges are layer-invariant)
    zero_kernel<<<(NNODES + 256) / 256, 256, 0, stream>>>(offs, pooled);
    hist_kernel<<<(NEDGES / 4 + 255) / 256, 256, 0, stream>>>(
        (const int4*)srcp, (const int4*)dstp, offs);
    scan1_kernel<<<SCAN_NB, SCAN_B, 0, stream>>>(offs, bsum);
    scan2_kernel<<<1, 256, 0, stream>>>(bsum, total);
    scan3_kernel<<<SCAN_NB, SCAN_B, 0, stream>>>(offs, bsum, total, cursors);
    scatter_kernel<<<(NEDGES / 4 + 255) / 256, 256, 0, stream>>>(
        (const int4*)srcp, (const int4*)dstp, (const float4*)eattr, cursors, csr);

    // 3 GAT layers (ping: matmul writes h2, aggregate writes hbuf which is next input)
    const float* hin = x;
    for (int l = 0; l < 3; ++l) {
        mm_alpha_kernel<<<NNODES / 16, 256, 0, stream>>>(hin, W[l], att[l], h2, ad, as_);
        gat_agg_kernel<<<NNODES / 4, 256, 0, stream>>>(h2, ad, as_, offs, csr,
                                                       att[l], bia[l], hbuf);
        hin = hbuf;
    }

    pool_kernel<<<(((NNODES + 63) / 64) + 3) / 4, 256, 0, stream>>>(hbuf, batch, pooled);
    final_kernel<<<1, 256, 0, stream>>>(pooled, Wf, bf, out);
}

// Round 8
// 839.726 us; speedup vs baseline: 1.0964x; 1.0964x over previous
//
#include <hip/hip_runtime.h>
#include <math.h>

#define NNODES 100000
#define NEDGES 1600000
#define DIM 64
#define NGRAPHS 64
#define NEG_SLOPE 0.2f
#define SCAN_B 512
#define SCAN_NB ((NNODES + SCAN_B - 1) / SCAN_B)
#define MM_NB (NNODES / 16)          // 6250 blocks for the fused mm0 part
#define SCATTER_NB (NEDGES / 256)    // 6250 blocks, 1 edge/thread

// ---------------- CSR construction (dst-sorted), self-loops excluded ----------------

__global__ void zero_kernel(int* __restrict__ counts, float* __restrict__ pooled) {
    int i = blockIdx.x * blockDim.x + threadIdx.x;
    if (i <= NNODES) counts[i] = 0;
    if (i < NGRAPHS * DIM) pooled[i] = 0.f;
}

// Histogram AND per-edge rank: atomicAdd's return value IS the edge's rank within
// its dst segment. Rank stored coalesced (int4); scatter pass needs no atomics.
__global__ void hist_kernel(const int4* __restrict__ src4, const int4* __restrict__ dst4,
                            int* __restrict__ counts, int4* __restrict__ rank4) {
    int e = blockIdx.x * blockDim.x + threadIdx.x;
    if (e < NEDGES / 4) {
        int4 s = src4[e], d = dst4[e];
        int4 r;
        r.x = (s.x != d.x) ? atomicAdd(&counts[d.x], 1) : 0;
        r.y = (s.y != d.y) ? atomicAdd(&counts[d.y], 1) : 0;
        r.z = (s.z != d.z) ? atomicAdd(&counts[d.z], 1) : 0;
        r.w = (s.w != d.w) ? atomicAdd(&counts[d.w], 1) : 0;
        rank4[e] = r;
    }
}

// In-place exclusive scan of counts -> per-block, plus block sums
__global__ void scan1_kernel(int* __restrict__ data, int* __restrict__ bsum) {
    __shared__ int tmp[SCAN_B];
    int t = threadIdx.x;
    int i = blockIdx.x * SCAN_B + t;
    int v = (i < NNODES) ? data[i] : 0;
    tmp[t] = v;
    __syncthreads();
    for (int off = 1; off < SCAN_B; off <<= 1) {
        int a = (t >= off) ? tmp[t - off] : 0;
        __syncthreads();
        if (t >= off) tmp[t] += a;
        __syncthreads();
    }
    if (i < NNODES) data[i] = tmp[t] - v;          // exclusive within block
    if (t == SCAN_B - 1) bsum[blockIdx.x] = tmp[t]; // block total
}

// One-block parallel exclusive scan of the SCAN_NB block sums (SCAN_NB <= 256)
__global__ void scan2_kernel(int* __restrict__ bsum, int* __restrict__ total) {
    __shared__ int tmp[256];
    int t = threadIdx.x;
    int v = (t < SCAN_NB) ? bsum[t] : 0;
    tmp[t] = v;
    __syncthreads();
    for (int off = 1; off < 256; off <<= 1) {
        int a = (t >= off) ? tmp[t - off] : 0;
        __syncthreads();
        if (t >= off) tmp[t] += a;
        __syncthreads();
    }
    if (t < SCAN_NB) bsum[t] = tmp[t] - v;  // exclusive
    if (t == 255) *total = tmp[t];
}

__global__ void scan3_kernel(int* __restrict__ offs, const int* __restrict__ bsum,
                             const int* __restrict__ total) {
    int i = blockIdx.x * SCAN_B + threadIdx.x;
    if (i < NNODES) offs[i] = offs[i] + bsum[blockIdx.x];
    if (i == 0) offs[NNODES] = *total;
}

// ---------------- FUSED: atomic-free CSR scatter + mm_alpha layer 0 -------------------
// Blocks [0, MM_NB): h2 = x @ W0 (+ alpha dots). Blocks [MM_NB, MM_NB+SCATTER_NB):
// CSR scatter (pos = offs[d] + rank[e], no atomic, fire-and-forget 8B store).
// The latency-bound scatter blocks leave VALU idle; mm0 compute hides under them.
__global__ __launch_bounds__(256) void scatter_mm_kernel(
        const int* __restrict__ src, const int* __restrict__ dst,
        const float* __restrict__ eattr, const int* __restrict__ rank,
        const int* __restrict__ offs, int2* __restrict__ csr,
        const float* __restrict__ hin, const float* __restrict__ W,
        const float* __restrict__ att,
        float* __restrict__ h2, float* __restrict__ ad, float* __restrict__ as_) {
    __shared__ float wl[DIM * DIM];
    __shared__ float hrow[4 * 4 * DIM];
    if (blockIdx.x >= MM_NB) {
        int e = (blockIdx.x - MM_NB) * 256 + threadIdx.x;
        int s = src[e], d = dst[e];
        if (s != d)
            csr[offs[d] + rank[e]] = make_int2(s, __float_as_int(eattr[e]));
        return;   // block-uniform branch: no barrier divergence
    }
    int t = threadIdx.x;
    for (int k = t; k < DIM * DIM; k += 256) wl[k] = W[k];
    __syncthreads();
    int lane = t & 63, w = t >> 6;
    float a0 = att[lane], a1 = att[DIM + lane];
    int rbase = blockIdx.x * 16 + w * 4;
    float* hw = &hrow[w * 4 * DIM];
    #pragma unroll
    for (int r = 0; r < 4; ++r)
        hw[r * DIM + lane] = hin[(size_t)(rbase + r) * DIM + lane];
    float acc0 = 0.f, acc1 = 0.f, acc2 = 0.f, acc3 = 0.f;
    #pragma unroll
    for (int k = 0; k < DIM; ++k) {
        float wlk = wl[k * DIM + lane];
        acc0 = fmaf(hw[0 * DIM + k], wlk, acc0);
        acc1 = fmaf(hw[1 * DIM + k], wlk, acc1);
        acc2 = fmaf(hw[2 * DIM + k], wlk, acc2);
        acc3 = fmaf(hw[3 * DIM + k], wlk, acc3);
    }
    float accs[4] = {acc0, acc1, acc2, acc3};
    #pragma unroll
    for (int r = 0; r < 4; ++r) {
        int i = rbase + r;
        float acc = accs[r];
        h2[(size_t)i * DIM + lane] = acc;
        float vd = acc * a0, vs = acc * a1;
        #pragma unroll
        for (int off = 32; off; off >>= 1) {
            vd += __shfl_xor(vd, off, 64);
            vs += __shfl_xor(vs, off, 64);
        }
        if (lane == 0) { ad[i] = vd; as_[i] = vs; }
    }
}

// ---------------- h2 = hin @ W; alpha_d = h2.att[:64]; alpha_s = h2.att[64:128] ----------------
__global__ __launch_bounds__(256) void mm_alpha_kernel(
        const float* __restrict__ hin, const float* __restrict__ W, const float* __restrict__ att,
        float* __restrict__ h2, float* __restrict__ ad, float* __restrict__ as_) {
    __shared__ float wl[DIM * DIM];
    __shared__ float hrow[4 * 4 * DIM];
    int t = threadIdx.x;
    for (int k = t; k < DIM * DIM; k += 256) wl[k] = W[k];
    __syncthreads();
    int lane = t & 63, w = t >> 6;
    float a0 = att[lane], a1 = att[DIM + lane];
    int rbase = blockIdx.x * 16 + w * 4;
    float* hw = &hrow[w * 4 * DIM];
    #pragma unroll
    for (int r = 0; r < 4; ++r)
        hw[r * DIM + lane] = hin[(size_t)(rbase + r) * DIM + lane];
    float acc0 = 0.f, acc1 = 0.f, acc2 = 0.f, acc3 = 0.f;
    #pragma unroll
    for (int k = 0; k < DIM; ++k) {
        float wlk = wl[k * DIM + lane];
        acc0 = fmaf(hw[0 * DIM + k], wlk, acc0);
        acc1 = fmaf(hw[1 * DIM + k], wlk, acc1);
        acc2 = fmaf(hw[2 * DIM + k], wlk, acc2);
        acc3 = fmaf(hw[3 * DIM + k], wlk, acc3);
    }
    float accs[4] = {acc0, acc1, acc2, acc3};
    #pragma unroll
    for (int r = 0; r < 4; ++r) {
        int i = rbase + r;
        float acc = accs[r];
        h2[(size_t)i * DIM + lane] = acc;
        float vd = acc * a0, vs = acc * a1;
        #pragma unroll
        for (int off = 32; off; off >>= 1) {
            vd += __shfl_xor(vd, off, 64);
            vs += __shfl_xor(vs, off, 64);
        }
        if (lane == 0) { ad[i] = vd; as_[i] = vs; }
    }
}

// ---------------- Per-node GAT aggregation: ONLINE softmax + weighted sum (single pass) ----------
__global__ __launch_bounds__(256) void gat_agg_kernel(
        const float* __restrict__ h2, const float* __restrict__ ad, const float* __restrict__ as_,
        const int* __restrict__ offs, const int2* __restrict__ csr,
        const float* __restrict__ att, const float* __restrict__ bias, float* __restrict__ hout) {
    int t = threadIdx.x, lane = t & 63, w = t >> 6;
    int i = blockIdx.x * 4 + w;
    float att2 = att[2 * DIM];
    int beg = offs[i], end = offs[i + 1];
    float adi = ad[i];
    float ls = adi + as_[i];                    // self-loop logit (edge feature 0)
    ls = ls >= 0.f ? ls : NEG_SLOPE * ls;
    float m = ls;
    float dsum = (lane == 0) ? 1.f : 0.f;       // exp(ls - ls) = 1, lane-partial
    float acc = h2[(size_t)i * DIM + lane];     // self contribution, weight 1
    for (int e0 = beg; e0 < end; e0 += 64) {
        int e = e0 + lane;
        float l = -INFINITY;
        int s = 0;
        if (e < end) {
            int2 sv = csr[e];                   // coalesced: contiguous per node
            s = sv.x;
            l = adi + as_[s] + __int_as_float(sv.y) * att2;
            l = l >= 0.f ? l : NEG_SLOPE * l;
        }
        float bm = l;
        #pragma unroll
        for (int off = 32; off; off >>= 1) bm = fmaxf(bm, __shfl_xor(bm, off, 64));
        if (bm > m + 8.f) {                     // deferred rescale (wave-uniform branch)
            float sc = __expf(m - bm);
            dsum *= sc; acc *= sc; m = bm;
        }
        float we = __expf(l - m);               // inactive lanes: exp(-inf) = 0
        dsum += we;
        int cnt = min(64, end - e0);
        for (int j = 0; j < cnt; ++j) {
            float wgt = __shfl(we, j, 64);
            int sj = __shfl(s, j, 64);
            acc = fmaf(wgt, h2[(size_t)sj * DIM + lane], acc);
        }
    }
    #pragma unroll
    for (int off = 32; off; off >>= 1) dsum += __shfl_xor(dsum, off, 64);
    float o = acc / dsum + bias[lane];
    hout[(size_t)i * DIM + lane] = fmaxf(o, 0.f);
}

// ---------------- global_add_pool (batch is sorted) + final linear ----------------

__global__ __launch_bounds__(256) void pool_kernel(const float* __restrict__ h,
                                                   const int* __restrict__ batch,
                                                   float* __restrict__ pooled) {
    int t = threadIdx.x, lane = t & 63, w = t >> 6;
    int chunk = blockIdx.x * 4 + w;
    int i0 = chunk * 64;
    if (i0 >= NNODES) return;
    int iend = min(NNODES, i0 + 64);
    int cur = batch[i0];
    float acc = 0.f;
    for (int i = i0; i < iend; ++i) {
        int g = batch[i];                  // sorted: few transitions per chunk
        if (g != cur) { atomicAdd(&pooled[cur * DIM + lane], acc); acc = 0.f; cur = g; }
        acc += h[(size_t)i * DIM + lane];
    }
    atomicAdd(&pooled[cur * DIM + lane], acc);
}

__global__ void final_kernel(const float* __restrict__ pooled, const float* __restrict__ Wf,
                             const float* __restrict__ bf, float* __restrict__ out) {
    int t = threadIdx.x, lane = t & 63, w = t >> 6;
    for (int g = w; g < NGRAPHS; g += 4) {
        float v = pooled[g * DIM + lane] * Wf[lane];
        #pragma unroll
        for (int off = 32; off; off >>= 1) v += __shfl_xor(v, off, 64);
        if (lane == 0) out[g] = v + bf[0];
    }
}

// ---------------- launch ----------------

extern "C" void kernel_launch(void* const* d_in, const int* in_sizes, int n_in,
                              void* d_out, int out_size, void* d_ws, size_t ws_size,
                              hipStream_t stream) {
    const float* x      = (const float*)d_in[0];
    const int*   ei     = (const int*)d_in[1];
    const float* eattr  = (const float*)d_in[2];
    const int*   batch  = (const int*)d_in[3];
    const float* W[3]   = {(const float*)d_in[4], (const float*)d_in[7], (const float*)d_in[10]};
    const float* att[3] = {(const float*)d_in[5], (const float*)d_in[8], (const float*)d_in[11]};
    const float* bia[3] = {(const float*)d_in[6], (const float*)d_in[9], (const float*)d_in[12]};
    const float* Wf = (const float*)d_in[13];
    const float* bf = (const float*)d_in[14];
    float* out = (float*)d_out;
    const int* srcp = ei;            // edge_index row 0
    const int* dstp = ei + NEDGES;   // edge_index row 1

    char* p = (char*)d_ws;
    auto alloc = [&](size_t bytes) { char* r = p; p += (bytes + 255) & ~size_t(255); return r; };
    int*   offs    = (int*)alloc((NNODES + 1) * sizeof(int));
    int*   rank    = (int*)alloc((size_t)NEDGES * sizeof(int));
    int*   bsum    = (int*)alloc(SCAN_NB * sizeof(int));
    int*   total   = (int*)alloc(sizeof(int));
    int2*  csr     = (int2*)alloc((size_t)NEDGES * sizeof(int2));
    float* h2      = (float*)alloc((size_t)NNODES * DIM * sizeof(float));
    float* ad      = (float*)alloc(NNODES * sizeof(float));
    float* as_     = (float*)alloc(NNODES * sizeof(float));
    float* hbuf    = (float*)alloc((size_t)NNODES * DIM * sizeof(float));
    float* pooled  = (float*)alloc(NGRAPHS * DIM * sizeof(float));

    // CSR build (same work every call; edges are layer-invariant)
    zero_kernel<<<(NNODES + 256) / 256, 256, 0, stream>>>(offs, pooled);
    hist_kernel<<<(NEDGES / 4 + 255) / 256, 256, 0, stream>>>(
        (const int4*)srcp, (const int4*)dstp, offs, (int4*)rank);
    scan1_kernel<<<SCAN_NB, SCAN_B, 0, stream>>>(offs, bsum);
    scan2_kernel<<<1, 256, 0, stream>>>(bsum, total);
    scan3_kernel<<<SCAN_NB, SCAN_B, 0, stream>>>(offs, bsum, total);

    // Fused: atomic-free CSR scatter + layer-0 matmul (independent work, co-scheduled)
    scatter_mm_kernel<<<MM_NB + SCATTER_NB, 256, 0, stream>>>(
        srcp, dstp, eattr, rank, offs, csr, x, W[0], att[0], h2, ad, as_);
    gat_agg_kernel<<<NNODES / 4, 256, 0, stream>>>(h2, ad, as_, offs, csr,
                                                   att[0], bia[0], hbuf);

    // Layers 1, 2
    for (int l = 1; l < 3; ++l) {
        mm_alpha_kernel<<<NNODES / 16, 256, 0, stream>>>(hbuf, W[l], att[l], h2, ad, as_);
        gat_agg_kernel<<<NNODES / 4, 256, 0, stream>>>(h2, ad, as_, offs, csr,
                                                       att[l], bia[l], hbuf);
    }

    pool_kernel<<<(((NNODES + 63) / 64) + 3) / 4, 256, 0, stream>>>(hbuf, batch, pooled);
    final_kernel<<<1, 256, 0, stream>>>(pooled, Wf, bf, out);
}

// Round 9
// 705.966 us; speedup vs baseline: 1.3041x; 1.1895x over previous
//
#include <hip/hip_runtime.h>
#include <math.h>

#define NNODES 100000
#define NEDGES 1600000
#define DIM 64
#define NGRAPHS 64
#define NEG_SLOPE 0.2f
#define SCAN_B 512
#define SCAN_NB ((NNODES + SCAN_B - 1) / SCAN_B)
#define MM_NB (NNODES / 16)                      // 6250 blocks for the fused mm0 part
#define SCATTER_NB ((NEDGES / 4 + 255) / 256)    // 1563 blocks, 4 edges/thread

// ---------------- CSR construction (dst-sorted), self-loops excluded ----------------

__global__ void zero_kernel(int* __restrict__ counts, float* __restrict__ pooled) {
    int i = blockIdx.x * blockDim.x + threadIdx.x;
    if (i <= NNODES) counts[i] = 0;
    if (i < NGRAPHS * DIM) pooled[i] = 0.f;
}

// Histogram AND per-edge rank: atomicAdd's return value IS the edge's rank within
// its dst segment. Rank stored coalesced (int4); scatter pass needs no atomics.
__global__ void hist_kernel(const int4* __restrict__ src4, const int4* __restrict__ dst4,
                            int* __restrict__ counts, int4* __restrict__ rank4) {
    int e = blockIdx.x * blockDim.x + threadIdx.x;
    if (e < NEDGES / 4) {
        int4 s = src4[e], d = dst4[e];
        int4 r;
        r.x = (s.x != d.x) ? atomicAdd(&counts[d.x], 1) : 0;
        r.y = (s.y != d.y) ? atomicAdd(&counts[d.y], 1) : 0;
        r.z = (s.z != d.z) ? atomicAdd(&counts[d.z], 1) : 0;
        r.w = (s.w != d.w) ? atomicAdd(&counts[d.w], 1) : 0;
        rank4[e] = r;
    }
}

// In-place exclusive scan of counts -> per-block, plus block sums
__global__ void scan1_kernel(int* __restrict__ data, int* __restrict__ bsum) {
    __shared__ int tmp[SCAN_B];
    int t = threadIdx.x;
    int i = blockIdx.x * SCAN_B + t;
    int v = (i < NNODES) ? data[i] : 0;
    tmp[t] = v;
    __syncthreads();
    for (int off = 1; off < SCAN_B; off <<= 1) {
        int a = (t >= off) ? tmp[t - off] : 0;
        __syncthreads();
        if (t >= off) tmp[t] += a;
        __syncthreads();
    }
    if (i < NNODES) data[i] = tmp[t] - v;          // exclusive within block
    if (t == SCAN_B - 1) bsum[blockIdx.x] = tmp[t]; // block total
}

// One-block parallel exclusive scan of the SCAN_NB block sums (SCAN_NB <= 256)
__global__ void scan2_kernel(int* __restrict__ bsum, int* __restrict__ total) {
    __shared__ int tmp[256];
    int t = threadIdx.x;
    int v = (t < SCAN_NB) ? bsum[t] : 0;
    tmp[t] = v;
    __syncthreads();
    for (int off = 1; off < 256; off <<= 1) {
        int a = (t >= off) ? tmp[t - off] : 0;
        __syncthreads();
        if (t >= off) tmp[t] += a;
        __syncthreads();
    }
    if (t < SCAN_NB) bsum[t] = tmp[t] - v;  // exclusive
    if (t == 255) *total = tmp[t];
}

__global__ void scan3_kernel(int* __restrict__ offs, const int* __restrict__ bsum,
                             const int* __restrict__ total) {
    int i = blockIdx.x * SCAN_B + threadIdx.x;
    if (i < NNODES) offs[i] = offs[i] + bsum[blockIdx.x];
    if (i == 0) offs[NNODES] = *total;
}

// ---------------- FUSED: atomic-free CSR scatter + mm_alpha layer 0 -------------------
// Blocks [0, MM_NB): h2 = x @ W0 (+ alpha dots). Blocks [MM_NB, MM_NB+SCATTER_NB):
// CSR scatter, 4 edges/thread (pos = offs[d] + rank[e]; no atomic; 4 independent
// fire-and-forget 8B stores per thread to counteract low wave occupancy).
__global__ __launch_bounds__(256) void scatter_mm_kernel(
        const int4* __restrict__ src4, const int4* __restrict__ dst4,
        const float4* __restrict__ eattr4, const int4* __restrict__ rank4,
        const int* __restrict__ offs, int2* __restrict__ csr,
        const float* __restrict__ hin, const float* __restrict__ W,
        const float* __restrict__ att,
        float* __restrict__ h2, float* __restrict__ ad, float* __restrict__ as_) {
    __shared__ float wl[DIM * DIM];
    __shared__ float hrow[4 * 4 * DIM];
    if (blockIdx.x >= MM_NB) {
        int e = (blockIdx.x - MM_NB) * 256 + threadIdx.x;
        if (e < NEDGES / 4) {
            int4 s = src4[e], d = dst4[e];
            int4 r = rank4[e];
            float4 v = eattr4[e];
            if (s.x != d.x) csr[offs[d.x] + r.x] = make_int2(s.x, __float_as_int(v.x));
            if (s.y != d.y) csr[offs[d.y] + r.y] = make_int2(s.y, __float_as_int(v.y));
            if (s.z != d.z) csr[offs[d.z] + r.z] = make_int2(s.z, __float_as_int(v.z));
            if (s.w != d.w) csr[offs[d.w] + r.w] = make_int2(s.w, __float_as_int(v.w));
        }
        return;   // block-uniform branch: no barrier divergence
    }
    int t = threadIdx.x;
    for (int k = t; k < DIM * DIM; k += 256) wl[k] = W[k];
    __syncthreads();
    int lane = t & 63, w = t >> 6;
    float a0 = att[lane], a1 = att[DIM + lane];
    int rbase = blockIdx.x * 16 + w * 4;
    float* hw = &hrow[w * 4 * DIM];
    #pragma unroll
    for (int r = 0; r < 4; ++r)
        hw[r * DIM + lane] = hin[(size_t)(rbase + r) * DIM + lane];
    float acc0 = 0.f, acc1 = 0.f, acc2 = 0.f, acc3 = 0.f;
    #pragma unroll
    for (int k = 0; k < DIM; ++k) {
        float wlk = wl[k * DIM + lane];
        acc0 = fmaf(hw[0 * DIM + k], wlk, acc0);
        acc1 = fmaf(hw[1 * DIM + k], wlk, acc1);
        acc2 = fmaf(hw[2 * DIM + k], wlk, acc2);
        acc3 = fmaf(hw[3 * DIM + k], wlk, acc3);
    }
    float accs[4] = {acc0, acc1, acc2, acc3};
    #pragma unroll
    for (int r = 0; r < 4; ++r) {
        int i = rbase + r;
        float acc = accs[r];
        h2[(size_t)i * DIM + lane] = acc;
        float vd = acc * a0, vs = acc * a1;
        #pragma unroll
        for (int off = 32; off; off >>= 1) {
            vd += __shfl_xor(vd, off, 64);
            vs += __shfl_xor(vs, off, 64);
        }
        if (lane == 0) { ad[i] = vd; as_[i] = vs; }
    }
}

// ---------------- h2 = hin @ W; alpha_d = h2.att[:64]; alpha_s = h2.att[64:128] ----------------
__global__ __launch_bounds__(256) void mm_alpha_kernel(
        const float* __restrict__ hin, const float* __restrict__ W, const float* __restrict__ att,
        float* __restrict__ h2, float* __restrict__ ad, float* __restrict__ as_) {
    __shared__ float wl[DIM * DIM];
    __shared__ float hrow[4 * 4 * DIM];
    int t = threadIdx.x;
    for (int k = t; k < DIM * DIM; k += 256) wl[k] = W[k];
    __syncthreads();
    int lane = t & 63, w = t >> 6;
    float a0 = att[lane], a1 = att[DIM + lane];
    int rbase = blockIdx.x * 16 + w * 4;
    float* hw = &hrow[w * 4 * DIM];
    #pragma unroll
    for (int r = 0; r < 4; ++r)
        hw[r * DIM + lane] = hin[(size_t)(rbase + r) * DIM + lane];
    float acc0 = 0.f, acc1 = 0.f, acc2 = 0.f, acc3 = 0.f;
    #pragma unroll
    for (int k = 0; k < DIM; ++k) {
        float wlk = wl[k * DIM + lane];
        acc0 = fmaf(hw[0 * DIM + k], wlk, acc0);
        acc1 = fmaf(hw[1 * DIM + k], wlk, acc1);
        acc2 = fmaf(hw[2 * DIM + k], wlk, acc2);
        acc3 = fmaf(hw[3 * DIM + k], wlk, acc3);
    }
    float accs[4] = {acc0, acc1, acc2, acc3};
    #pragma unroll
    for (int r = 0; r < 4; ++r) {
        int i = rbase + r;
        float acc = accs[r];
        h2[(size_t)i * DIM + lane] = acc;
        float vd = acc * a0, vs = acc * a1;
        #pragma unroll
        for (int off = 32; off; off >>= 1) {
            vd += __shfl_xor(vd, off, 64);
            vs += __shfl_xor(vs, off, 64);
        }
        if (lane == 0) { ad[i] = vd; as_[i] = vs; }
    }
}

// ---------------- Per-node GAT aggregation: ONLINE softmax + weighted sum (single pass) ----------
// One wave per node; lane = channel. Inner loop software-pipelined 8-deep:
// 8 independent h2 gathers issued into registers, then 8 FMAs (MLP 1 -> 8).
__global__ __launch_bounds__(256) void gat_agg_kernel(
        const float* __restrict__ h2, const float* __restrict__ ad, const float* __restrict__ as_,
        const int* __restrict__ offs, const int2* __restrict__ csr,
        const float* __restrict__ att, const float* __restrict__ bias, float* __restrict__ hout) {
    int t = threadIdx.x, lane = t & 63, w = t >> 6;
    int i = blockIdx.x * 4 + w;
    float att2 = att[2 * DIM];
    int beg = offs[i], end = offs[i + 1];
    float adi = ad[i];
    float ls = adi + as_[i];                    // self-loop logit (edge feature 0)
    ls = ls >= 0.f ? ls : NEG_SLOPE * ls;
    float m = ls;
    float dsum = (lane == 0) ? 1.f : 0.f;       // exp(ls - ls) = 1, lane-partial
    float acc = h2[(size_t)i * DIM + lane];     // self contribution, weight 1
    for (int e0 = beg; e0 < end; e0 += 64) {
        int e = e0 + lane;
        float l = -INFINITY;
        int s = 0;
        if (e < end) {
            int2 sv = csr[e];                   // coalesced: contiguous per node
            s = sv.x;
            l = adi + as_[s] + __int_as_float(sv.y) * att2;
            l = l >= 0.f ? l : NEG_SLOPE * l;
        }
        float bm = l;
        #pragma unroll
        for (int off = 32; off; off >>= 1) bm = fmaxf(bm, __shfl_xor(bm, off, 64));
        if (bm > m + 8.f) {                     // deferred rescale (wave-uniform branch)
            float sc = __expf(m - bm);
            dsum *= sc; acc *= sc; m = bm;
        }
        float we = __expf(l - m);               // inactive lanes: exp(-inf) = 0
        dsum += we;
        int cnt = min(64, end - e0);
        int j = 0;
        while (j + 8 <= cnt) {                  // 8-deep pipelined gathers
            float v[8];
            #pragma unroll
            for (int k = 0; k < 8; ++k) {
                int sj = __shfl(s, j + k, 64);
                v[k] = h2[(size_t)sj * DIM + lane];
            }
            #pragma unroll
            for (int k = 0; k < 8; ++k) {
                float wgt = __shfl(we, j + k, 64);
                acc = fmaf(wgt, v[k], acc);
            }
            j += 8;
        }
        for (; j < cnt; ++j) {                  // tail (< 8 edges)
            float wgt = __shfl(we, j, 64);
            int sj = __shfl(s, j, 64);
            acc = fmaf(wgt, h2[(size_t)sj * DIM + lane], acc);
        }
    }
    #pragma unroll
    for (int off = 32; off; off >>= 1) dsum += __shfl_xor(dsum, off, 64);
    float o = acc / dsum + bias[lane];
    hout[(size_t)i * DIM + lane] = fmaxf(o, 0.f);
}

// ---------------- global_add_pool (batch is sorted) + final linear ----------------

__global__ __launch_bounds__(256) void pool_kernel(const float* __restrict__ h,
                                                   const int* __restrict__ batch,
                                                   float* __restrict__ pooled) {
    int t = threadIdx.x, lane = t & 63, w = t >> 6;
    int chunk = blockIdx.x * 4 + w;
    int i0 = chunk * 64;
    if (i0 >= NNODES) return;
    int iend = min(NNODES, i0 + 64);
    int cur = batch[i0];
    float acc = 0.f;
    for (int i = i0; i < iend; ++i) {
        int g = batch[i];                  // sorted: few transitions per chunk
        if (g != cur) { atomicAdd(&pooled[cur * DIM + lane], acc); acc = 0.f; cur = g; }
        acc += h[(size_t)i * DIM + lane];
    }
    atomicAdd(&pooled[cur * DIM + lane], acc);
}

__global__ void final_kernel(const float* __restrict__ pooled, const float* __restrict__ Wf,
                             const float* __restrict__ bf, float* __restrict__ out) {
    int t = threadIdx.x, lane = t & 63, w = t >> 6;
    for (int g = w; g < NGRAPHS; g += 4) {
        float v = pooled[g * DIM + lane] * Wf[lane];
        #pragma unroll
        for (int off = 32; off; off >>= 1) v += __shfl_xor(v, off, 64);
        if (lane == 0) out[g] = v + bf[0];
    }
}

// ---------------- launch ----------------

extern "C" void kernel_launch(void* const* d_in, const int* in_sizes, int n_in,
                              void* d_out, int out_size, void* d_ws, size_t ws_size,
                              hipStream_t stream) {
    const float* x      = (const float*)d_in[0];
    const int*   ei     = (const int*)d_in[1];
    const float* eattr  = (const float*)d_in[2];
    const int*   batch  = (const int*)d_in[3];
    const float* W[3]   = {(const float*)d_in[4], (const float*)d_in[7], (const float*)d_in[10]};
    const float* att[3] = {(const float*)d_in[5], (const float*)d_in[8], (const float*)d_in[11]};
    const float* bia[3] = {(const float*)d_in[6], (const float*)d_in[9], (const float*)d_in[12]};
    const float* Wf = (const float*)d_in[13];
    const float* bf = (const float*)d_in[14];
    float* out = (float*)d_out;
    const int* srcp = ei;            // edge_index row 0
    const int* dstp = ei + NEDGES;   // edge_index row 1

    char* p = (char*)d_ws;
    auto alloc = [&](size_t bytes) { char* r = p; p += (bytes + 255) & ~size_t(255); return r; };
    int*   offs    = (int*)alloc((NNODES + 1) * sizeof(int));
    int*   rank    = (int*)alloc((size_t)NEDGES * sizeof(int));
    int*   bsum    = (int*)alloc(SCAN_NB * sizeof(int));
    int*   total   = (int*)alloc(sizeof(int));
    int2*  csr     = (int2*)alloc((size_t)NEDGES * sizeof(int2));
    float* h2      = (float*)alloc((size_t)NNODES * DIM * sizeof(float));
    float* ad      = (float*)alloc(NNODES * sizeof(float));
    float* as_     = (float*)alloc(NNODES * sizeof(float));
    float* hbuf    = (float*)alloc((size_t)NNODES * DIM * sizeof(float));
    float* pooled  = (float*)alloc(NGRAPHS * DIM * sizeof(float));

    // CSR build (same work every call; edges are layer-invariant)
    zero_kernel<<<(NNODES + 256) / 256, 256, 0, stream>>>(offs, pooled);
    hist_kernel<<<(NEDGES / 4 + 255) / 256, 256, 0, stream>>>(
        (const int4*)srcp, (const int4*)dstp, offs, (int4*)rank);
    scan1_kernel<<<SCAN_NB, SCAN_B, 0, stream>>>(offs, bsum);
    scan2_kernel<<<1, 256, 0, stream>>>(bsum, total);
    scan3_kernel<<<SCAN_NB, SCAN_B, 0, stream>>>(offs, bsum, total);

    // Fused: atomic-free CSR scatter + layer-0 matmul (independent work, co-scheduled)
    scatter_mm_kernel<<<MM_NB + SCATTER_NB, 256, 0, stream>>>(
        (const int4*)srcp, (const int4*)dstp, (const float4*)eattr, (const int4*)rank,
        offs, csr, x, W[0], att[0], h2, ad, as_);
    gat_agg_kernel<<<NNODES / 4, 256, 0, stream>>>(h2, ad, as_, offs, csr,
                                                   att[0], bia[0], hbuf);

    // Layers 1, 2
    for (int l = 1; l < 3; ++l) {
        mm_alpha_kernel<<<NNODES / 16, 256, 0, stream>>>(hbuf, W[l], att[l], h2, ad, as_);
        gat_agg_kernel<<<NNODES / 4, 256, 0, stream>>>(h2, ad, as_, offs, csr,
                                                       att[l], bia[l], hbuf);
    }

    pool_kernel<<<(((NNODES + 63) / 64) + 3) / 4, 256, 0, stream>>>(hbuf, batch, pooled);
    final_kernel<<<1, 256, 0, stream>>>(pooled, Wf, bf, out);
}

// Round 10
// 596.162 us; speedup vs baseline: 1.5443x; 1.1842x over previous
//
#include <hip/hip_runtime.h>
#include <math.h>

#define NNODES 100000
#define NEDGES 1600000
#define DIM 64
#define NGRAPHS 64
#define NEG_SLOPE 0.2f
#define SCAN_B 512
#define SCAN_NB ((NNODES + SCAN_B - 1) / SCAN_B)
#define MM_NB (NNODES / 16)                      // 6250 blocks for the fused mm0 part
#define SCATTER_NB ((NEDGES / 4 + 255) / 256)    // 1563 blocks, 4 edges/thread

// ---------------- CSR construction (dst-sorted), self-loops excluded ----------------

__global__ void zero_kernel(int* __restrict__ counts, float* __restrict__ pooled) {
    int i = blockIdx.x * blockDim.x + threadIdx.x;
    if (i <= NNODES) counts[i] = 0;
    if (i < NGRAPHS * DIM) pooled[i] = 0.f;
}

// Histogram AND per-edge rank: atomicAdd's return value IS the edge's rank within
// its dst segment. Rank stored coalesced (int4); scatter pass needs no atomics.
__global__ void hist_kernel(const int4* __restrict__ src4, const int4* __restrict__ dst4,
                            int* __restrict__ counts, int4* __restrict__ rank4) {
    int e = blockIdx.x * blockDim.x + threadIdx.x;
    if (e < NEDGES / 4) {
        int4 s = src4[e], d = dst4[e];
        int4 r;
        r.x = (s.x != d.x) ? atomicAdd(&counts[d.x], 1) : 0;
        r.y = (s.y != d.y) ? atomicAdd(&counts[d.y], 1) : 0;
        r.z = (s.z != d.z) ? atomicAdd(&counts[d.z], 1) : 0;
        r.w = (s.w != d.w) ? atomicAdd(&counts[d.w], 1) : 0;
        rank4[e] = r;
    }
}

// In-place exclusive scan of counts -> per-block, plus block sums
__global__ void scan1_kernel(int* __restrict__ data, int* __restrict__ bsum) {
    __shared__ int tmp[SCAN_B];
    int t = threadIdx.x;
    int i = blockIdx.x * SCAN_B + t;
    int v = (i < NNODES) ? data[i] : 0;
    tmp[t] = v;
    __syncthreads();
    for (int off = 1; off < SCAN_B; off <<= 1) {
        int a = (t >= off) ? tmp[t - off] : 0;
        __syncthreads();
        if (t >= off) tmp[t] += a;
        __syncthreads();
    }
    if (i < NNODES) data[i] = tmp[t] - v;          // exclusive within block
    if (t == SCAN_B - 1) bsum[blockIdx.x] = tmp[t]; // block total
}

// One-block parallel exclusive scan of the SCAN_NB block sums (SCAN_NB <= 256)
__global__ void scan2_kernel(int* __restrict__ bsum, int* __restrict__ total) {
    __shared__ int tmp[256];
    int t = threadIdx.x;
    int v = (t < SCAN_NB) ? bsum[t] : 0;
    tmp[t] = v;
    __syncthreads();
    for (int off = 1; off < 256; off <<= 1) {
        int a = (t >= off) ? tmp[t - off] : 0;
        __syncthreads();
        if (t >= off) tmp[t] += a;
        __syncthreads();
    }
    if (t < SCAN_NB) bsum[t] = tmp[t] - v;  // exclusive
    if (t == 255) *total = tmp[t];
}

__global__ void scan3_kernel(int* __restrict__ offs, const int* __restrict__ bsum,
                             const int* __restrict__ total) {
    int i = blockIdx.x * SCAN_B + threadIdx.x;
    if (i < NNODES) offs[i] = offs[i] + bsum[blockIdx.x];
    if (i == 0) offs[NNODES] = *total;
}

// ---------------- FUSED: atomic-free CSR scatter + mm_alpha layer 0 -------------------
// Blocks [0, SCATTER_NB): CSR scatter FIRST in dispatch order (latency-bound; hides
// under the mm blocks that follow). Blocks [SCATTER_NB, ...): h2 = x @ W0 + alpha dots.
// launch_bounds(256,4): cap VGPR ~128 so scatter blocks get decent occupancy.
__global__ __launch_bounds__(256, 4) void scatter_mm_kernel(
        const int4* __restrict__ src4, const int4* __restrict__ dst4,
        const float4* __restrict__ eattr4, const int4* __restrict__ rank4,
        const int* __restrict__ offs, int2* __restrict__ csr,
        const float* __restrict__ hin, const float* __restrict__ W,
        const float* __restrict__ att,
        float* __restrict__ h2, float* __restrict__ ad, float* __restrict__ as_) {
    __shared__ float wl[DIM * DIM];
    __shared__ float hrow[4 * 4 * DIM];
    if (blockIdx.x < SCATTER_NB) {
        int e = blockIdx.x * 256 + threadIdx.x;
        if (e < NEDGES / 4) {
            int4 s = src4[e], d = dst4[e];
            int4 r = rank4[e];
            float4 v = eattr4[e];
            if (s.x != d.x) csr[offs[d.x] + r.x] = make_int2(s.x, __float_as_int(v.x));
            if (s.y != d.y) csr[offs[d.y] + r.y] = make_int2(s.y, __float_as_int(v.y));
            if (s.z != d.z) csr[offs[d.z] + r.z] = make_int2(s.z, __float_as_int(v.z));
            if (s.w != d.w) csr[offs[d.w] + r.w] = make_int2(s.w, __float_as_int(v.w));
        }
        return;   // block-uniform branch: no barrier divergence
    }
    int blk = blockIdx.x - SCATTER_NB;
    int t = threadIdx.x;
    for (int k = t; k < DIM * DIM; k += 256) wl[k] = W[k];
    __syncthreads();
    int lane = t & 63, w = t >> 6;
    float a0 = att[lane], a1 = att[DIM + lane];
    int rbase = blk * 16 + w * 4;
    float* hw = &hrow[w * 4 * DIM];
    #pragma unroll
    for (int r = 0; r < 4; ++r)
        hw[r * DIM + lane] = hin[(size_t)(rbase + r) * DIM + lane];
    float acc0 = 0.f, acc1 = 0.f, acc2 = 0.f, acc3 = 0.f;
    #pragma unroll 16
    for (int k = 0; k < DIM; ++k) {
        float wlk = wl[k * DIM + lane];
        acc0 = fmaf(hw[0 * DIM + k], wlk, acc0);
        acc1 = fmaf(hw[1 * DIM + k], wlk, acc1);
        acc2 = fmaf(hw[2 * DIM + k], wlk, acc2);
        acc3 = fmaf(hw[3 * DIM + k], wlk, acc3);
    }
    float accs[4] = {acc0, acc1, acc2, acc3};
    #pragma unroll
    for (int r = 0; r < 4; ++r) {
        int i = rbase + r;
        float acc = accs[r];
        h2[(size_t)i * DIM + lane] = acc;
        float vd = acc * a0, vs = acc * a1;
        #pragma unroll
        for (int off = 32; off; off >>= 1) {
            vd += __shfl_xor(vd, off, 64);
            vs += __shfl_xor(vs, off, 64);
        }
        if (lane == 0) { ad[i] = vd; as_[i] = vs; }
    }
}

// ---------------- Per-node GAT aggregation + FUSED next-layer matmul ------------------
// One wave per node; lane = channel. Online softmax (deferred-max, THR=8), 8-deep
// pipelined gathers. Epilogue: if Wnext != null, compute h2next[i] = relu(o) @ Wnext
// per-node (row-local, no sync needed) + next layer's alpha dots; else write hout.
__global__ __launch_bounds__(256) void gat_agg_kernel(
        const float* __restrict__ h2, const float* __restrict__ ad, const float* __restrict__ as_,
        const int* __restrict__ offs, const int2* __restrict__ csr,
        const float* __restrict__ att, const float* __restrict__ bias,
        const float* __restrict__ Wnext, const float* __restrict__ attNext,
        float* __restrict__ h2next, float* __restrict__ adNext, float* __restrict__ asNext,
        float* __restrict__ hout) {
    __shared__ float wl[DIM * DIM];
    __shared__ float hrow[4 * DIM];
    int t = threadIdx.x, lane = t & 63, w = t >> 6;
    if (Wnext) {                                 // block-uniform: stage next-layer W
        for (int k = t; k < DIM * DIM; k += 256) wl[k] = Wnext[k];
        __syncthreads();
    }
    float a0n = 0.f, a1n = 0.f;
    if (Wnext) { a0n = attNext[lane]; a1n = attNext[DIM + lane]; }
    int i = blockIdx.x * 4 + w;
    float att2 = att[2 * DIM];
    int beg = offs[i], end = offs[i + 1];
    float adi = ad[i];
    float ls = adi + as_[i];                    // self-loop logit (edge feature 0)
    ls = ls >= 0.f ? ls : NEG_SLOPE * ls;
    float m = ls;
    float dsum = (lane == 0) ? 1.f : 0.f;       // exp(ls - ls) = 1, lane-partial
    float acc = h2[(size_t)i * DIM + lane];     // self contribution, weight 1
    for (int e0 = beg; e0 < end; e0 += 64) {
        int e = e0 + lane;
        float l = -INFINITY;
        int s = 0;
        if (e < end) {
            int2 sv = csr[e];                   // coalesced: contiguous per node
            s = sv.x;
            l = adi + as_[s] + __int_as_float(sv.y) * att2;
            l = l >= 0.f ? l : NEG_SLOPE * l;
        }
        float bm = l;
        #pragma unroll
        for (int off = 32; off; off >>= 1) bm = fmaxf(bm, __shfl_xor(bm, off, 64));
        if (bm > m + 8.f) {                     // deferred rescale (wave-uniform branch)
            float sc = __expf(m - bm);
            dsum *= sc; acc *= sc; m = bm;
        }
        float we = __expf(l - m);               // inactive lanes: exp(-inf) = 0
        dsum += we;
        int cnt = min(64, end - e0);
        int j = 0;
        while (j + 8 <= cnt) {                  // 8-deep pipelined gathers
            float v[8];
            #pragma unroll
            for (int k = 0; k < 8; ++k) {
                int sj = __shfl(s, j + k, 64);
                v[k] = h2[(size_t)sj * DIM + lane];
            }
            #pragma unroll
            for (int k = 0; k < 8; ++k) {
                float wgt = __shfl(we, j + k, 64);
                acc = fmaf(wgt, v[k], acc);
            }
            j += 8;
        }
        for (; j < cnt; ++j) {                  // tail (< 8 edges)
            float wgt = __shfl(we, j, 64);
            int sj = __shfl(s, j, 64);
            acc = fmaf(wgt, h2[(size_t)sj * DIM + lane], acc);
        }
    }
    #pragma unroll
    for (int off = 32; off; off >>= 1) dsum += __shfl_xor(dsum, off, 64);
    float o = fmaxf(acc / dsum + bias[lane], 0.f);   // this layer's relu'd output
    if (!Wnext) {
        hout[(size_t)i * DIM + lane] = o;
        return;
    }
    // Fused next-layer matmul: row i only -> per-node, no grid sync needed.
    hrow[w * DIM + lane] = o;                   // same-wave LDS RAW: ordered
    float h2v = 0.f;
    #pragma unroll 8
    for (int k = 0; k < DIM; ++k)
        h2v = fmaf(hrow[w * DIM + k], wl[k * DIM + lane], h2v);
    h2next[(size_t)i * DIM + lane] = h2v;
    float vd = h2v * a0n, vs = h2v * a1n;
    #pragma unroll
    for (int off = 32; off; off >>= 1) {
        vd += __shfl_xor(vd, off, 64);
        vs += __shfl_xor(vs, off, 64);
    }
    if (lane == 0) { adNext[i] = vd; asNext[i] = vs; }
}

// ---------------- global_add_pool (batch is sorted) + final linear ----------------

__global__ __launch_bounds__(256) void pool_kernel(const float* __restrict__ h,
                                                   const int* __restrict__ batch,
                                                   float* __restrict__ pooled) {
    int t = threadIdx.x, lane = t & 63, w = t >> 6;
    int chunk = blockIdx.x * 4 + w;
    int i0 = chunk * 64;
    if (i0 >= NNODES) return;
    int iend = min(NNODES, i0 + 64);
    int cur = batch[i0];
    float acc = 0.f;
    for (int i = i0; i < iend; ++i) {
        int g = batch[i];                  // sorted: few transitions per chunk
        if (g != cur) { atomicAdd(&pooled[cur * DIM + lane], acc); acc = 0.f; cur = g; }
        acc += h[(size_t)i * DIM + lane];
    }
    atomicAdd(&pooled[cur * DIM + lane], acc);
}

__global__ void final_kernel(const float* __restrict__ pooled, const float* __restrict__ Wf,
                             const float* __restrict__ bf, float* __restrict__ out) {
    int t = threadIdx.x, lane = t & 63, w = t >> 6;
    for (int g = w; g < NGRAPHS; g += 4) {
        float v = pooled[g * DIM + lane] * Wf[lane];
        #pragma unroll
        for (int off = 32; off; off >>= 1) v += __shfl_xor(v, off, 64);
        if (lane == 0) out[g] = v + bf[0];
    }
}

// ---------------- launch ----------------

extern "C" void kernel_launch(void* const* d_in, const int* in_sizes, int n_in,
                              void* d_out, int out_size, void* d_ws, size_t ws_size,
                              hipStream_t stream) {
    const float* x      = (const float*)d_in[0];
    const int*   ei     = (const int*)d_in[1];
    const float* eattr  = (const float*)d_in[2];
    const int*   batch  = (const int*)d_in[3];
    const float* W[3]   = {(const float*)d_in[4], (const float*)d_in[7], (const float*)d_in[10]};
    const float* att[3] = {(const float*)d_in[5], (const float*)d_in[8], (const float*)d_in[11]};
    const float* bia[3] = {(const float*)d_in[6], (const float*)d_in[9], (const float*)d_in[12]};
    const float* Wf = (const float*)d_in[13];
    const float* bf = (const float*)d_in[14];
    float* out = (float*)d_out;
    const int* srcp = ei;            // edge_index row 0
    const int* dstp = ei + NEDGES;   // edge_index row 1

    char* p = (char*)d_ws;
    auto alloc = [&](size_t bytes) { char* r = p; p += (bytes + 255) & ~size_t(255); return r; };
    int*   offs    = (int*)alloc((NNODES + 1) * sizeof(int));
    int*   rank    = (int*)alloc((size_t)NEDGES * sizeof(int));
    int*   bsum    = (int*)alloc(SCAN_NB * sizeof(int));
    int*   total   = (int*)alloc(sizeof(int));
    int2*  csr     = (int2*)alloc((size_t)NEDGES * sizeof(int2));
    float* h2a     = (float*)alloc((size_t)NNODES * DIM * sizeof(float));
    float* ad_a    = (float*)alloc(NNODES * sizeof(float));
    float* as_a    = (float*)alloc(NNODES * sizeof(float));
    float* h2b     = (float*)alloc((size_t)NNODES * DIM * sizeof(float));
    float* ad_b    = (float*)alloc(NNODES * sizeof(float));
    float* as_b    = (float*)alloc(NNODES * sizeof(float));
    float* pooled  = (float*)alloc(NGRAPHS * DIM * sizeof(float));

    // CSR build (same work every call; edges are layer-invariant)
    zero_kernel<<<(NNODES + 256) / 256, 256, 0, stream>>>(offs, pooled);
    hist_kernel<<<(NEDGES / 4 + 255) / 256, 256, 0, stream>>>(
        (const int4*)srcp, (const int4*)dstp, offs, (int4*)rank);
    scan1_kernel<<<SCAN_NB, SCAN_B, 0, stream>>>(offs, bsum);
    scan2_kernel<<<1, 256, 0, stream>>>(bsum, total);
    scan3_kernel<<<SCAN_NB, SCAN_B, 0, stream>>>(offs, bsum, total);

    // Fused: atomic-free CSR scatter (dispatched first) + layer-0 matmul
    scatter_mm_kernel<<<SCATTER_NB + MM_NB, 256, 0, stream>>>(
        (const int4*)srcp, (const int4*)dstp, (const float4*)eattr, (const int4*)rank,
        offs, csr, x, W[0], att[0], h2a, ad_a, as_a);

    // agg0 (layer0) + fused mm1:  h2a -> h2b
    gat_agg_kernel<<<NNODES / 4, 256, 0, stream>>>(
        h2a, ad_a, as_a, offs, csr, att[0], bia[0],
        W[1], att[1], h2b, ad_b, as_b, (float*)nullptr);
    // agg1 (layer1) + fused mm2:  h2b -> h2a
    gat_agg_kernel<<<NNODES / 4, 256, 0, stream>>>(
        h2b, ad_b, as_b, offs, csr, att[1], bia[1],
        W[2], att[2], h2a, ad_a, as_a, (float*)nullptr);
    // agg2 (layer2, plain): h2a -> h2b (= final node features)
    gat_agg_kernel<<<NNODES / 4, 256, 0, stream>>>(
        h2a, ad_a, as_a, offs, csr, att[2], bia[2],
        (const float*)nullptr, (const float*)nullptr,
        (float*)nullptr, (float*)nullptr, (float*)nullptr, h2b);

    pool_kernel<<<(((NNODES + 63) / 64) + 3) / 4, 256, 0, stream>>>(h2b, batch, pooled);
    final_kernel<<<1, 256, 0, stream>>>(pooled, Wf, bf, out);
}

// Round 12
// 594.245 us; speedup vs baseline: 1.5493x; 1.0032x over previous
//
#include <hip/hip_runtime.h>
#include <math.h>

#define NNODES 100000
#define NEDGES 1600000
#define DIM 64
#define NGRAPHS 64
#define NEG_SLOPE 0.2f
#define SCAN_B 512
#define SCAN_NB ((NNODES + SCAN_B - 1) / SCAN_B)
#define MM_NB (NNODES / 16)                      // 6250 blocks for the fused mm0 part
#define SCATTER_NB ((NEDGES / 4 + 255) / 256)    // 1563 blocks, 4 edges/thread

// ---------------- CSR construction (dst-sorted), self-loops excluded ----------------

__global__ void zero_kernel(int* __restrict__ counts, float* __restrict__ pooled) {
    int i = blockIdx.x * blockDim.x + threadIdx.x;
    if (i <= NNODES) counts[i] = 0;
    if (i < NGRAPHS * DIM) pooled[i] = 0.f;
}

// Histogram AND per-edge rank: atomicAdd's return value IS the edge's rank within
// its dst segment. Rank stored coalesced (int4); scatter pass needs no atomics.
__global__ void hist_kernel(const int4* __restrict__ src4, const int4* __restrict__ dst4,
                            int* __restrict__ counts, int4* __restrict__ rank4) {
    int e = blockIdx.x * blockDim.x + threadIdx.x;
    if (e < NEDGES / 4) {
        int4 s = src4[e], d = dst4[e];
        int4 r;
        r.x = (s.x != d.x) ? atomicAdd(&counts[d.x], 1) : 0;
        r.y = (s.y != d.y) ? atomicAdd(&counts[d.y], 1) : 0;
        r.z = (s.z != d.z) ? atomicAdd(&counts[d.z], 1) : 0;
        r.w = (s.w != d.w) ? atomicAdd(&counts[d.w], 1) : 0;
        rank4[e] = r;
    }
}

// In-place exclusive scan of counts -> per-block, plus block sums
__global__ void scan1_kernel(int* __restrict__ data, int* __restrict__ bsum) {
    __shared__ int tmp[SCAN_B];
    int t = threadIdx.x;
    int i = blockIdx.x * SCAN_B + t;
    int v = (i < NNODES) ? data[i] : 0;
    tmp[t] = v;
    __syncthreads();
    for (int off = 1; off < SCAN_B; off <<= 1) {
        int a = (t >= off) ? tmp[t - off] : 0;
        __syncthreads();
        if (t >= off) tmp[t] += a;
        __syncthreads();
    }
    if (i < NNODES) data[i] = tmp[t] - v;          // exclusive within block
    if (t == SCAN_B - 1) bsum[blockIdx.x] = tmp[t]; // block total
}

// One-block parallel exclusive scan of the SCAN_NB block sums (SCAN_NB <= 256)
__global__ void scan2_kernel(int* __restrict__ bsum, int* __restrict__ total) {
    __shared__ int tmp[256];
    int t = threadIdx.x;
    int v = (t < SCAN_NB) ? bsum[t] : 0;
    tmp[t] = v;
    __syncthreads();
    for (int off = 1; off < 256; off <<= 1) {
        int a = (t >= off) ? tmp[t - off] : 0;
        __syncthreads();
        if (t >= off) tmp[t] += a;
        __syncthreads();
    }
    if (t < SCAN_NB) bsum[t] = tmp[t] - v;  // exclusive
    if (t == 255) *total = tmp[t];
}

__global__ void scan3_kernel(int* __restrict__ offs, const int* __restrict__ bsum,
                             const int* __restrict__ total) {
    int i = blockIdx.x * SCAN_B + threadIdx.x;
    if (i < NNODES) offs[i] = offs[i] + bsum[blockIdx.x];
    if (i == 0) offs[NNODES] = *total;
}

// ---------------- FUSED: atomic-free CSR scatter + mm_alpha layer 0 -------------------
__global__ __launch_bounds__(256, 4) void scatter_mm_kernel(
        const int4* __restrict__ src4, const int4* __restrict__ dst4,
        const float4* __restrict__ eattr4, const int4* __restrict__ rank4,
        const int* __restrict__ offs, int2* __restrict__ csr,
        const float* __restrict__ hin, const float* __restrict__ W,
        const float* __restrict__ att,
        float* __restrict__ h2, float* __restrict__ ad, float* __restrict__ as_) {
    __shared__ float wl[DIM * DIM];
    __shared__ float hrow[4 * 4 * DIM];
    if (blockIdx.x < SCATTER_NB) {
        int e = blockIdx.x * 256 + threadIdx.x;
        if (e < NEDGES / 4) {
            int4 s = src4[e], d = dst4[e];
            int4 r = rank4[e];
            float4 v = eattr4[e];
            if (s.x != d.x) csr[offs[d.x] + r.x] = make_int2(s.x, __float_as_int(v.x));
            if (s.y != d.y) csr[offs[d.y] + r.y] = make_int2(s.y, __float_as_int(v.y));
            if (s.z != d.z) csr[offs[d.z] + r.z] = make_int2(s.z, __float_as_int(v.z));
            if (s.w != d.w) csr[offs[d.w] + r.w] = make_int2(s.w, __float_as_int(v.w));
        }
        return;   // block-uniform branch: no barrier divergence
    }
    int blk = blockIdx.x - SCATTER_NB;
    int t = threadIdx.x;
    for (int k = t; k < DIM * DIM; k += 256) wl[k] = W[k];
    __syncthreads();
    int lane = t & 63, w = t >> 6;
    float a0 = att[lane], a1 = att[DIM + lane];
    int rbase = blk * 16 + w * 4;
    float* hw = &hrow[w * 4 * DIM];
    #pragma unroll
    for (int r = 0; r < 4; ++r)
        hw[r * DIM + lane] = hin[(size_t)(rbase + r) * DIM + lane];
    float acc0 = 0.f, acc1 = 0.f, acc2 = 0.f, acc3 = 0.f;
    #pragma unroll 16
    for (int k = 0; k < DIM; ++k) {
        float wlk = wl[k * DIM + lane];
        acc0 = fmaf(hw[0 * DIM + k], wlk, acc0);
        acc1 = fmaf(hw[1 * DIM + k], wlk, acc1);
        acc2 = fmaf(hw[2 * DIM + k], wlk, acc2);
        acc3 = fmaf(hw[3 * DIM + k], wlk, acc3);
    }
    float accs[4] = {acc0, acc1, acc2, acc3};
    #pragma unroll
    for (int r = 0; r < 4; ++r) {
        int i = rbase + r;
        float acc = accs[r];
        h2[(size_t)i * DIM + lane] = acc;
        float vd = acc * a0, vs = acc * a1;
        #pragma unroll
        for (int off = 32; off; off >>= 1) {
            vd += __shfl_xor(vd, off, 64);
            vs += __shfl_xor(vs, off, 64);
        }
        if (lane == 0) { ad[i] = vd; as_[i] = vs; }
    }
}

// ---------------- Per-node GAT aggregation + FUSED next-layer matmul ------------------
// One wave per node; lane = channel. Online softmax with ballot fast-path (full
// max-reduce only when a rescale is needed). Gathers double-buffered: 16 loads in
// flight per wave (batch k+1 issued before batch k is consumed).
__global__ __launch_bounds__(256) void gat_agg_kernel(
        const float* __restrict__ h2, const float* __restrict__ ad, const float* __restrict__ as_,
        const int* __restrict__ offs, const int2* __restrict__ csr,
        const float* __restrict__ att, const float* __restrict__ bias,
        const float* __restrict__ Wnext, const float* __restrict__ attNext,
        float* __restrict__ h2next, float* __restrict__ adNext, float* __restrict__ asNext,
        float* __restrict__ hout) {
    __shared__ float wl[DIM * DIM];
    __shared__ float hrow[4 * DIM];
    int t = threadIdx.x, lane = t & 63, w = t >> 6;
    if (Wnext) {                                 // block-uniform: stage next-layer W
        for (int k = t; k < DIM * DIM; k += 256) wl[k] = Wnext[k];
        __syncthreads();
    }
    float a0n = 0.f, a1n = 0.f;
    if (Wnext) { a0n = attNext[lane]; a1n = attNext[DIM + lane]; }
    int i = blockIdx.x * 4 + w;
    float att2 = att[2 * DIM];
    int beg = offs[i], end = offs[i + 1];
    float adi = ad[i];
    float ls = adi + as_[i];                    // self-loop logit (edge feature 0)
    ls = ls >= 0.f ? ls : NEG_SLOPE * ls;
    float m = ls;
    float dsum = (lane == 0) ? 1.f : 0.f;       // exp(ls - ls) = 1, lane-partial
    float acc = h2[(size_t)i * DIM + lane];     // self contribution, weight 1
    for (int e0 = beg; e0 < end; e0 += 64) {
        int e = e0 + lane;
        float l = -INFINITY;
        int s = 0;
        if (e < end) {
            int2 sv = csr[e];                   // coalesced: contiguous per node
            s = sv.x;
            l = adi + as_[s] + __int_as_float(sv.y) * att2;
            l = l >= 0.f ? l : NEG_SLOPE * l;
        }
        if (__any(l > m + 8.f)) {               // rare: rescale actually needed
            float bm = l;
            #pragma unroll
            for (int off = 32; off; off >>= 1) bm = fmaxf(bm, __shfl_xor(bm, off, 64));
            float sc = __expf(m - bm);
            dsum *= sc; acc *= sc; m = bm;
        }
        float we = __expf(l - m);               // inactive lanes: exp(-inf) = 0
        dsum += we;
        int cnt = min(64, end - e0);
        float va[8], vb[8];
        if (cnt >= 8) {                         // preload batch 0
            #pragma unroll
            for (int k = 0; k < 8; ++k) {
                int sj = __shfl(s, k, 64);
                va[k] = h2[(size_t)sj * DIM + lane];
            }
        }
        int j = 0;
        while (j + 8 <= cnt) {
            bool hasNext = (j + 16 <= cnt);
            if (hasNext) {                      // issue next batch BEFORE consuming
                #pragma unroll
                for (int k = 0; k < 8; ++k) {
                    int sj = __shfl(s, j + 8 + k, 64);
                    vb[k] = h2[(size_t)sj * DIM + lane];
                }
            }
            #pragma unroll
            for (int k = 0; k < 8; ++k) {
                float wgt = __shfl(we, j + k, 64);
                acc = fmaf(wgt, va[k], acc);
            }
            if (hasNext) {
                #pragma unroll
                for (int k = 0; k < 8; ++k) va[k] = vb[k];
            }
            j += 8;
        }
        for (; j < cnt; ++j) {                  // tail (< 8 edges)
            float wgt = __shfl(we, j, 64);
            int sj = __shfl(s, j, 64);
            acc = fmaf(wgt, h2[(size_t)sj * DIM + lane], acc);
        }
    }
    #pragma unroll
    for (int off = 32; off; off >>= 1) dsum += __shfl_xor(dsum, off, 64);
    float o = fmaxf(acc / dsum + bias[lane], 0.f);   // this layer's relu'd output
    if (!Wnext) {
        hout[(size_t)i * DIM + lane] = o;
        return;
    }
    // Fused next-layer matmul: row i only -> per-node, no grid sync needed.
    hrow[w * DIM + lane] = o;                   // same-wave LDS RAW: ordered
    float h2v = 0.f;
    #pragma unroll 8
    for (int k = 0; k < DIM; ++k)
        h2v = fmaf(hrow[w * DIM + k], wl[k * DIM + lane], h2v);
    h2next[(size_t)i * DIM + lane] = h2v;
    float vd = h2v * a0n, vs = h2v * a1n;
    #pragma unroll
    for (int off = 32; off; off >>= 1) {
        vd += __shfl_xor(vd, off, 64);
        vs += __shfl_xor(vs, off, 64);
    }
    if (lane == 0) { adNext[i] = vd; asNext[i] = vs; }
}

// ---------------- global_add_pool (batch is sorted) + final linear ----------------

__global__ __launch_bounds__(256) void pool_kernel(const float* __restrict__ h,
                                                   const int* __restrict__ batch,
                                                   float* __restrict__ pooled) {
    int t = threadIdx.x, lane = t & 63, w = t >> 6;
    int chunk = blockIdx.x * 4 + w;
    int i0 = chunk * 64;
    if (i0 >= NNODES) return;
    int iend = min(NNODES, i0 + 64);
    int cur = batch[i0];
    float acc = 0.f;
    for (int i = i0; i < iend; ++i) {
        int g = batch[i];                  // sorted: few transitions per chunk
        if (g != cur) { atomicAdd(&pooled[cur * DIM + lane], acc); acc = 0.f; cur = g; }
        acc += h[(size_t)i * DIM + lane];
    }
    atomicAdd(&pooled[cur * DIM + lane], acc);
}

__global__ void final_kernel(const float* __restrict__ pooled, const float* __restrict__ Wf,
                             const float* __restrict__ bf, float* __restrict__ out) {
    int t = threadIdx.x, lane = t & 63, w = t >> 6;
    for (int g = w; g < NGRAPHS; g += 4) {
        float v = pooled[g * DIM + lane] * Wf[lane];
        #pragma unroll
        for (int off = 32; off; off >>= 1) v += __shfl_xor(v, off, 64);
        if (lane == 0) out[g] = v + bf[0];
    }
}

// ---------------- launch ----------------

extern "C" void kernel_launch(void* const* d_in, const int* in_sizes, int n_in,
                              void* d_out, int out_size, void* d_ws, size_t ws_size,
                              hipStream_t stream) {
    const float* x      = (const float*)d_in[0];
    const int*   ei     = (const int*)d_in[1];
    const float* eattr  = (const float*)d_in[2];
    const int*   batch  = (const int*)d_in[3];
    const float* W[3]   = {(const float*)d_in[4], (const float*)d_in[7], (const float*)d_in[10]};
    const float* att[3] = {(const float*)d_in[5], (const float*)d_in[8], (const float*)d_in[11]};
    const float* bia[3] = {(const float*)d_in[6], (const float*)d_in[9], (const float*)d_in[12]};
    const float* Wf = (const float*)d_in[13];
    const float* bf = (const float*)d_in[14];
    float* out = (float*)d_out;
    const int* srcp = ei;            // edge_index row 0
    const int* dstp = ei + NEDGES;   // edge_index row 1

    char* p = (char*)d_ws;
    auto alloc = [&](size_t bytes) { char* r = p; p += (bytes + 255) & ~size_t(255); return r; };
    int*   offs    = (int*)alloc((NNODES + 1) * sizeof(int));
    int*   rank    = (int*)alloc((size_t)NEDGES * sizeof(int));
    int*   bsum    = (int*)alloc(SCAN_NB * sizeof(int));
    int*   total   = (int*)alloc(sizeof(int));
    int2*  csr     = (int2*)alloc((size_t)NEDGES * sizeof(int2));
    float* h2a     = (float*)alloc((size_t)NNODES * DIM * sizeof(float));
    float* ad_a    = (float*)alloc(NNODES * sizeof(float));
    float* as_a    = (float*)alloc(NNODES * sizeof(float));
    float* h2b     = (float*)alloc((size_t)NNODES * DIM * sizeof(float));
    float* ad_b    = (float*)alloc(NNODES * sizeof(float));
    float* as_b    = (float*)alloc(NNODES * sizeof(float));
    float* pooled  = (float*)alloc(NGRAPHS * DIM * sizeof(float));

    // CSR build (same work every call; edges are layer-invariant)
    zero_kernel<<<(NNODES + 256) / 256, 256, 0, stream>>>(offs, pooled);
    hist_kernel<<<(NEDGES / 4 + 255) / 256, 256, 0, stream>>>(
        (const int4*)srcp, (const int4*)dstp, offs, (int4*)rank);
    scan1_kernel<<<SCAN_NB, SCAN_B, 0, stream>>>(offs, bsum);
    scan2_kernel<<<1, 256, 0, stream>>>(bsum, total);
    scan3_kernel<<<SCAN_NB, SCAN_B, 0, stream>>>(offs, bsum, total);

    // Fused: atomic-free CSR scatter (dispatched first) + layer-0 matmul
    scatter_mm_kernel<<<SCATTER_NB + MM_NB, 256, 0, stream>>>(
        (const int4*)srcp, (const int4*)dstp, (const float4*)eattr, (const int4*)rank,
        offs, csr, x, W[0], att[0], h2a, ad_a, as_a);

    // agg0 (layer0) + fused mm1:  h2a -> h2b
    gat_agg_kernel<<<NNODES / 4, 256, 0, stream>>>(
        h2a, ad_a, as_a, offs, csr, att[0], bia[0],
        W[1], att[1], h2b, ad_b, as_b, (float*)nullptr);
    // agg1 (layer1) + fused mm2:  h2b -> h2a
    gat_agg_kernel<<<NNODES / 4, 256, 0, stream>>>(
        h2b, ad_b, as_b, offs, csr, att[1], bia[1],
        W[2], att[2], h2a, ad_a, as_a, (float*)nullptr);
    // agg2 (layer2, plain): h2a -> h2b (= final node features)
    gat_agg_kernel<<<NNODES / 4, 256, 0, stream>>>(
        h2a, ad_a, as_a, offs, csr, att[2], bia[2],
        (const float*)nullptr, (const float*)nullptr,
        (float*)nullptr, (float*)nullptr, (float*)nullptr, h2b);

    pool_kernel<<<(((NNODES + 63) / 64) + 3) / 4, 256, 0, stream>>>(h2b, batch, pooled);
    final_kernel<<<1, 256, 0, stream>>>(pooled, Wf, bf, out);
}